// Round 4
// baseline (440.401 us; speedup 1.0000x reference)
//
#include <hip/hip_runtime.h>
#include <math.h>
#include <stdint.h>

// Problem constants (fixed by setup_inputs)
#define NN   20000   // nodes
#define DEG  32      // neighbors per node
#define DIN  70      // 2*3 + 64 concat features
#define KP   96      // DIN padded (fallback path)
#define DH   256     // hidden
#define DC   64      // channels
#define NT   512     // threads per block (8 waves)
#define ET   128     // edges per block
#define NPB  4       // nodes per block

typedef _Float16 f16;
typedef _Float16 f16x4 __attribute__((ext_vector_type(4)));
typedef _Float16 f16x8 __attribute__((ext_vector_type(8)));
typedef float    f32x4 __attribute__((ext_vector_type(4)));

// f16 workspace layout (element offsets)
#define W1T_OFF 0
#define W2T_OFF (256*KP)
#define W3T_OFF (256*KP + 256*DH)
#define WS_F16_TOTAL (256*KP + 256*DH + DC*DH)
#define P_OFF   WS_F16_TOTAL                     // P: [NN][DH] f16

#define LUTE 2049      // entries on [-8,8], step 1/128

__device__ __forceinline__ float gelu_fast(float v) {
    // exact gelu via A&S 7.1.26 erf, |err| < 1.5e-7 (LUT build + fallback only)
    float u  = v * 0.70710678118654752f;
    float a  = fabsf(u);
    float t  = __builtin_amdgcn_rcpf(fmaf(0.3275911f, a, 1.0f));
    float p  = fmaf(1.061405429f, t, -1.453152027f);
    p = fmaf(p, t, 1.421413741f);
    p = fmaf(p, t, -0.284496736f);
    p = fmaf(p, t, 0.254829592f);
    p = p * t;
    float e  = __expf(-u * u);
    float er = fmaf(-p, e, 1.0f);
    er = copysignf(er, u);
    return 0.5f * v * (1.0f + er);
}

__device__ __forceinline__ float gelu_lut(const float* __restrict__ lut, float v) {
    float s  = fmaf(v, 128.0f, 1024.0f);
    s = fminf(fmaxf(s, 0.0f), 2047.999f);
    float jf = floorf(s);
    float fr = s - jf;
    int j = (int)jf;
    float a = lut[j], b = lut[j + 1];    // -> ds_read2_b32
    float g = fmaf(fr, b - a, a);
    g = (v >  8.0f) ? v    : g;
    g = (v < -8.0f) ? 0.0f : g;
    return g;
}

__device__ __forceinline__ uint32_t pack2h(float a, float b) {
    f16 lo = (f16)a, hi = (f16)b;
    return (uint32_t)__builtin_bit_cast(uint16_t, lo)
         | ((uint32_t)__builtin_bit_cast(uint16_t, hi) << 16);
}

// swizzled s_h addressing: row pitch 512 B, byte_col ^= (row&7)<<4
__device__ __forceinline__ f16* h_at(f16* base, int row, int col) {
    uint32_t off = (uint32_t)(row << 9) + ((uint32_t)(col << 1) ^ (uint32_t)((row & 7) << 4));
    return (f16*)((char*)base + off);
}

// ---- pre-kernel: fp32 weights -> transposed f16 in workspace ----
__global__ void prep_weights(const float* __restrict__ W1,
                             const float* __restrict__ W2,
                             const float* __restrict__ W3,
                             f16* __restrict__ ws)
{
    int t = blockIdx.x * blockDim.x + threadIdx.x;
    if (t < W2T_OFF) {                       // w1t: [256][96] (fallback path)
        int n = t / KP, k = t - n * KP;
        ws[t] = (k < DIN) ? (f16)W1[k * DH + n] : (f16)0.0f;
    } else if (t < W3T_OFF) {                // w2t: [256][256]
        int u = t - W2T_OFF;
        int n = u >> 8, k = u & 255;
        ws[t] = (f16)W2[k * DH + n];
    } else if (t < WS_F16_TOTAL) {           // w3t: [64][256]
        int u = t - W3T_OFF;
        int n = u >> 8, k = u & 255;
        ws[t] = (f16)W3[k * DC + n];
    }
}

// ---- pre-kernel: P[n][c] = y[n]@W1[0:3] + f[n]@W1[6:70], f16 ----
__global__ void prep_P(const float* __restrict__ y,
                       const float* __restrict__ f_y,
                       const float* __restrict__ W1,
                       f16* __restrict__ P)
{
    int node = blockIdx.x * 4 + (threadIdx.x >> 6);
    int lane = threadIdx.x & 63;
    if (node >= NN) return;
    int c0 = lane * 4;
    float4 acc = {0.f, 0.f, 0.f, 0.f};
    #pragma unroll
    for (int k = 0; k < 3; ++k) {
        float yv = y[node * 3 + k];
        float4 wv = *(const float4*)&W1[k * DH + c0];
        acc.x = fmaf(yv, wv.x, acc.x); acc.y = fmaf(yv, wv.y, acc.y);
        acc.z = fmaf(yv, wv.z, acc.z); acc.w = fmaf(yv, wv.w, acc.w);
    }
    float fv = f_y[node * DC + lane];        // lane holds f[node][lane] (lane<64)
    #pragma unroll 8
    for (int j = 0; j < DC; ++j) {
        float fj = __shfl(fv, j, 64);
        float4 wv = *(const float4*)&W1[(6 + j) * DH + c0];
        acc.x = fmaf(fj, wv.x, acc.x); acc.y = fmaf(fj, wv.y, acc.y);
        acc.z = fmaf(fj, wv.z, acc.z); acc.w = fmaf(fj, wv.w, acc.w);
    }
    f16x4 pv; pv[0] = (f16)acc.x; pv[1] = (f16)acc.y; pv[2] = (f16)acc.z; pv[3] = (f16)acc.w;
    *(f16x4*)&P[(size_t)node * DH + c0] = pv;
}

// ---- main fused kernel (P/Q path) ----
__global__ __launch_bounds__(NT, 4)
void it_mfma2_kernel(const float* __restrict__ x,
                     const float* __restrict__ f_y,
                     const float* __restrict__ wq,
                     const int*   __restrict__ nbr,
                     const float* __restrict__ W1,
                     const float* __restrict__ b1,
                     const float* __restrict__ b2,
                     const float* __restrict__ b3,
                     const f16*  __restrict__ ws,
                     float* __restrict__ out)
{
    const int blk  = blockIdx.x;
    const int t    = threadIdx.x;
    const int lane = t & 63;
    const int w    = t >> 6;
    const int l15  = lane & 15;
    const int lk   = lane >> 4;

    const f16* w2t = ws + W2T_OFF;
    const f16* w3t = ws + W3T_OFF;
    const f16* P   = ws + P_OFF;

    __shared__ __align__(16) f16 s_h[ET][DH];     // 64 KB, swizzled
    __shared__ float s_lut[2052];                 // 8.2 KB
    __shared__ float s_q[NPB][DH];                // 4 KB
    __shared__ int   s_nbr[ET];
    __shared__ float s_wq[ET];
    __shared__ float s_red[8][DC];
    f16* s_h0 = &s_h[0][0];

    // ---- phase A: nbr/wq, LUT build, Q rows ----
    if (t < ET) {
        int n = nbr[blk * ET + t];
        s_nbr[t] = n;
        s_wq[t]  = wq[n];
    }
    for (int i = t; i < LUTE; i += NT)
        s_lut[i] = gelu_fast((float)i * 0.0078125f - 8.0f);
    for (int idx = t; idx < NPB * DH; idx += NT) {
        int node = idx >> 8, c = idx & 255;
        int g = blk * NPB + node;
        float q = b1[c];
        q = fmaf(x[g * 3 + 0], W1[3 * DH + c], q);
        q = fmaf(x[g * 3 + 1], W1[4 * DH + c], q);
        q = fmaf(x[g * 3 + 2], W1[5 * DH + c], q);
        s_q[node][c] = q;
    }
    __syncthreads();

    // ---- phase B: h1 = gelu(P[nbr] + Q[node]) directly into swizzled s_h ----
    {
        const int e    = t >> 2;
        const int part = t & 3;
        const int node = e >> 5;
        const f16* Prow = P + (size_t)s_nbr[e] * DH;
        #pragma unroll
        for (int p = 0; p < 8; ++p) {
            int c = part * 64 + p * 8;
            f16x8 pv = *(const f16x8*)&Prow[c];
            f32x4 q0 = *(const f32x4*)&s_q[node][c];
            f32x4 q1 = *(const f32x4*)&s_q[node][c + 4];
            f16x8 hv;
            #pragma unroll
            for (int j = 0; j < 4; ++j)
                hv[j] = (f16)gelu_lut(s_lut, (float)pv[j] + q0[j]);
            #pragma unroll
            for (int j = 0; j < 4; ++j)
                hv[4 + j] = (f16)gelu_lut(s_lut, (float)pv[4 + j] + q1[j]);
            *(f16x8*)h_at(s_h0, e, c) = hv;
        }
    }
    __syncthreads();

    // wave partition: 2 M-groups x 4 N-groups
    const int m_base = (w >> 2) * 64;
    const int n_base = (w & 3) * 64;

    f32x4 acc[4][4];

    // ---- stage 2: h2 = gelu(h1 @ W2 + b2), K = 256 (swapped mfma) ----
    #pragma unroll
    for (int nj = 0; nj < 4; ++nj) {
        float4 bv = *(const float4*)&b2[n_base + nj*16 + lk*4];
        #pragma unroll
        for (int mi = 0; mi < 4; ++mi) acc[mi][nj] = (f32x4){bv.x, bv.y, bv.z, bv.w};
    }
    #pragma unroll 2
    for (int ks = 0; ks < DH/32; ++ks) {
        const int k0 = ks*32 + lk*8;
        f16x8 a[4], b[4];
        #pragma unroll
        for (int mi = 0; mi < 4; ++mi)
            a[mi] = *(const f16x8*)h_at(s_h0, m_base + mi*16 + l15, k0);
        #pragma unroll
        for (int nj = 0; nj < 4; ++nj)
            b[nj] = *(const f16x8*)&w2t[(n_base + nj*16 + l15) * DH + k0];
        #pragma unroll
        for (int mi = 0; mi < 4; ++mi)
            #pragma unroll
            for (int nj = 0; nj < 4; ++nj)
                acc[mi][nj] = __builtin_amdgcn_mfma_f32_16x16x32_f16(b[nj], a[mi], acc[mi][nj], 0, 0, 0);
    }
    __syncthreads();   // all waves done reading h1 before overwrite
    #pragma unroll
    for (int mi = 0; mi < 4; ++mi)
        #pragma unroll
        for (int nj = 0; nj < 4; ++nj) {
            int e  = m_base + mi*16 + l15;
            int n0 = n_base + nj*16 + lk*4;
            f16x4 hv;
            #pragma unroll
            for (int r = 0; r < 4; ++r) hv[r] = (f16)gelu_lut(s_lut, acc[mi][nj][r]);
            *(f16x4*)h_at(s_h0, e, n0) = hv;
        }
    __syncthreads();

    // ---- stage 3: k3 = h2 @ W3 + b3; msg = wq*k3*f; segment reduce ----
    {
        float fv[4][4]; float wqe[4];
        #pragma unroll
        for (int r = 0; r < 4; ++r) {
            int e = w*16 + lk*4 + r;
            int n = s_nbr[e];
            wqe[r] = s_wq[e];
            #pragma unroll
            for (int nj = 0; nj < 4; ++nj)
                fv[r][nj] = f_y[n * DC + nj*16 + l15];
        }
        f32x4 acc3[4];
        #pragma unroll
        for (int nj = 0; nj < 4; ++nj) {
            float bv = b3[nj*16 + l15];
            acc3[nj] = (f32x4){bv, bv, bv, bv};
        }
        #pragma unroll 2
        for (int ks = 0; ks < DH/32; ++ks) {
            const int k0 = ks*32 + lk*8;
            f16x8 a = *(const f16x8*)h_at(s_h0, w*16 + l15, k0);
            #pragma unroll
            for (int nj = 0; nj < 4; ++nj) {
                f16x8 b = *(const f16x8*)&w3t[(nj*16 + l15) * DH + k0];
                acc3[nj] = __builtin_amdgcn_mfma_f32_16x16x32_f16(a, b, acc3[nj], 0, 0, 0);
            }
        }
        float part[4];
        #pragma unroll
        for (int nj = 0; nj < 4; ++nj) {
            float s = 0.f;
            #pragma unroll
            for (int r = 0; r < 4; ++r)
                s = fmaf(wqe[r] * acc3[nj][r], fv[r][nj], s);
            part[nj] = s;
        }
        #pragma unroll
        for (int nj = 0; nj < 4; ++nj) {
            part[nj] += __shfl_xor(part[nj], 16, 64);
            part[nj] += __shfl_xor(part[nj], 32, 64);
        }
        if (lane < 16) {
            #pragma unroll
            for (int nj = 0; nj < 4; ++nj) s_red[w][nj*16 + l15] = part[nj];
        }
    }
    __syncthreads();

    if (t < NPB * DC) {
        int node = t >> 6, c = t & 63;
        out[(blk * NPB + node) * DC + c] = s_red[2*node][c] + s_red[2*node + 1][c];
    }
}

// ---- fallback kernel (round-3 path, used if ws too small for P) ----
__global__ __launch_bounds__(NT, 4)
void it_mfma_fallback(const float* __restrict__ y,
                      const float* __restrict__ x,
                      const float* __restrict__ f_y,
                      const float* __restrict__ wq,
                      const int*   __restrict__ nbr,
                      const float* __restrict__ b1,
                      const float* __restrict__ b2,
                      const float* __restrict__ b3,
                      const f16*  __restrict__ ws,
                      float* __restrict__ out)
{
    const int blk  = blockIdx.x;
    const int t    = threadIdx.x;
    const int lane = t & 63;
    const int w    = t >> 6;
    const int l15  = lane & 15;
    const int lk   = lane >> 4;
    const f16* w1t = ws + W1T_OFF;
    const f16* w2t = ws + W2T_OFF;
    const f16* w3t = ws + W3T_OFF;
    #define AGG_P 104
    #define H_P   264
    __shared__ __align__(16) unsigned char s_u[ET * H_P * 2];
    f16 (*s_agg)[AGG_P] = (f16(*)[AGG_P])s_u;
    f16 (*s_h)[H_P]     = (f16(*)[H_P])s_u;
    __shared__ int   s_nbr[ET];
    __shared__ float s_wq[ET];
    __shared__ float s_red[8][DC];
    if (t < ET) { int n = nbr[blk * ET + t]; s_nbr[t] = n; s_wq[t] = wq[n]; }
    __syncthreads();
    {
        uint32_t* aggu = (uint32_t*)&s_agg[0][0];
        #pragma unroll
        for (int p = 0; p < 8; ++p) {
            int idx = t + p * NT;
            int e = idx >> 5, c2 = idx & 31;
            int n = s_nbr[e];
            float2 fvv = *(const float2*)&f_y[n * DC + 2 * c2];
            aggu[e * 52 + 3 + c2] = pack2h(fvv.x, fvv.y);
        }
        if (t < ET) {
            int e = t, n = s_nbr[e];
            int node = blk * NPB + (e >> 5);
            aggu[e*52 + 0] = pack2h(y[n*3], y[n*3+1]);
            aggu[e*52 + 1] = pack2h(y[n*3+2], x[node*3]);
            aggu[e*52 + 2] = pack2h(x[node*3+1], x[node*3+2]);
            #pragma unroll
            for (int c = 35; c < 48; ++c) aggu[e*52 + c] = 0;
        }
    }
    __syncthreads();
    const int m_base = (w >> 2) * 64;
    const int n_base = (w & 3) * 64;
    f32x4 acc[4][4];
    #pragma unroll
    for (int nj = 0; nj < 4; ++nj) {
        float4 bv = *(const float4*)&b1[n_base + nj*16 + lk*4];
        #pragma unroll
        for (int mi = 0; mi < 4; ++mi) acc[mi][nj] = (f32x4){bv.x, bv.y, bv.z, bv.w};
    }
    #pragma unroll
    for (int ks = 0; ks < KP/32; ++ks) {
        const int k0 = ks*32 + lk*8;
        f16x8 a[4], b[4];
        #pragma unroll
        for (int mi = 0; mi < 4; ++mi) a[mi] = *(const f16x8*)&s_agg[m_base + mi*16 + l15][k0];
        #pragma unroll
        for (int nj = 0; nj < 4; ++nj) b[nj] = *(const f16x8*)&w1t[(n_base + nj*16 + l15) * KP + k0];
        #pragma unroll
        for (int mi = 0; mi < 4; ++mi)
            #pragma unroll
            for (int nj = 0; nj < 4; ++nj)
                acc[mi][nj] = __builtin_amdgcn_mfma_f32_16x16x32_f16(b[nj], a[mi], acc[mi][nj], 0, 0, 0);
    }
    __syncthreads();
    #pragma unroll
    for (int mi = 0; mi < 4; ++mi)
        #pragma unroll
        for (int nj = 0; nj < 4; ++nj) {
            int e = m_base + mi*16 + l15, n0 = n_base + nj*16 + lk*4;
            f16x4 hv;
            #pragma unroll
            for (int r = 0; r < 4; ++r) hv[r] = (f16)gelu_fast(acc[mi][nj][r]);
            *(f16x4*)&s_h[e][n0] = hv;
        }
    __syncthreads();
    #pragma unroll
    for (int nj = 0; nj < 4; ++nj) {
        float4 bv = *(const float4*)&b2[n_base + nj*16 + lk*4];
        #pragma unroll
        for (int mi = 0; mi < 4; ++mi) acc[mi][nj] = (f32x4){bv.x, bv.y, bv.z, bv.w};
    }
    #pragma unroll 2
    for (int ks = 0; ks < DH/32; ++ks) {
        const int k0 = ks*32 + lk*8;
        f16x8 a[4], b[4];
        #pragma unroll
        for (int mi = 0; mi < 4; ++mi) a[mi] = *(const f16x8*)&s_h[m_base + mi*16 + l15][k0];
        #pragma unroll
        for (int nj = 0; nj < 4; ++nj) b[nj] = *(const f16x8*)&w2t[(n_base + nj*16 + l15) * DH + k0];
        #pragma unroll
        for (int mi = 0; mi < 4; ++mi)
            #pragma unroll
            for (int nj = 0; nj < 4; ++nj)
                acc[mi][nj] = __builtin_amdgcn_mfma_f32_16x16x32_f16(b[nj], a[mi], acc[mi][nj], 0, 0, 0);
    }
    __syncthreads();
    #pragma unroll
    for (int mi = 0; mi < 4; ++mi)
        #pragma unroll
        for (int nj = 0; nj < 4; ++nj) {
            int e = m_base + mi*16 + l15, n0 = n_base + nj*16 + lk*4;
            f16x4 hv;
            #pragma unroll
            for (int r = 0; r < 4; ++r) hv[r] = (f16)gelu_fast(acc[mi][nj][r]);
            *(f16x4*)&s_h[e][n0] = hv;
        }
    __syncthreads();
    {
        float fv[4][4]; float wqe[4];
        #pragma unroll
        for (int r = 0; r < 4; ++r) {
            int e = w*16 + lk*4 + r, n = s_nbr[e];
            wqe[r] = s_wq[e];
            #pragma unroll
            for (int nj = 0; nj < 4; ++nj) fv[r][nj] = f_y[n * DC + nj*16 + l15];
        }
        f32x4 acc3[4];
        #pragma unroll
        for (int nj = 0; nj < 4; ++nj) { float bv = b3[nj*16 + l15]; acc3[nj] = (f32x4){bv, bv, bv, bv}; }
        #pragma unroll 2
        for (int ks = 0; ks < DH/32; ++ks) {
            const int k0 = ks*32 + lk*8;
            f16x8 a = *(const f16x8*)&s_h[w*16 + l15][k0];
            #pragma unroll
            for (int nj = 0; nj < 4; ++nj) {
                f16x8 b = *(const f16x8*)&w3t[(nj*16 + l15) * DH + k0];
                acc3[nj] = __builtin_amdgcn_mfma_f32_16x16x32_f16(a, b, acc3[nj], 0, 0, 0);
            }
        }
        float part[4];
        #pragma unroll
        for (int nj = 0; nj < 4; ++nj) {
            float s = 0.f;
            #pragma unroll
            for (int r = 0; r < 4; ++r) s = fmaf(wqe[r] * acc3[nj][r], fv[r][nj], s);
            part[nj] = s;
        }
        #pragma unroll
        for (int nj = 0; nj < 4; ++nj) {
            part[nj] += __shfl_xor(part[nj], 16, 64);
            part[nj] += __shfl_xor(part[nj], 32, 64);
        }
        if (lane < 16) {
            #pragma unroll
            for (int nj = 0; nj < 4; ++nj) s_red[w][nj*16 + l15] = part[nj];
        }
    }
    __syncthreads();
    if (t < NPB * DC) {
        int node = t >> 6, c = t & 63;
        out[(blk * NPB + node) * DC + c] = s_red[2*node][c] + s_red[2*node + 1][c];
    }
}

extern "C" void kernel_launch(void* const* d_in, const int* in_sizes, int n_in,
                              void* d_out, int out_size, void* d_ws, size_t ws_size,
                              hipStream_t stream) {
    const float* y   = (const float*)d_in[0];
    const float* x   = (const float*)d_in[1];
    const float* f_y = (const float*)d_in[2];
    const float* wq  = (const float*)d_in[3];
    const int*   nbr = (const int*)d_in[4];
    const float* W1  = (const float*)d_in[6];
    const float* b1  = (const float*)d_in[7];
    const float* W2  = (const float*)d_in[8];
    const float* b2  = (const float*)d_in[9];
    const float* W3  = (const float*)d_in[10];
    const float* b3  = (const float*)d_in[11];
    float* out = (float*)d_out;
    f16*   ws  = (f16*)d_ws;

    hipLaunchKernelGGL(prep_weights, dim3((WS_F16_TOTAL + 255) / 256), dim3(256), 0, stream,
                       W1, W2, W3, ws);

    size_t need_bytes = ((size_t)WS_F16_TOTAL + (size_t)NN * DH) * sizeof(f16);
    if (ws_size >= need_bytes) {
        hipLaunchKernelGGL(prep_P, dim3((NN + 3) / 4), dim3(256), 0, stream,
                           y, f_y, W1, ws + P_OFF);
        hipLaunchKernelGGL(it_mfma2_kernel, dim3(NN / NPB), dim3(NT), 0, stream,
                           x, f_y, wq, nbr, W1, b1, b2, b3, ws, out);
    } else {
        hipLaunchKernelGGL(it_mfma_fallback, dim3(NN / NPB), dim3(NT), 0, stream,
                           y, x, f_y, wq, nbr, b1, b2, b3, ws, out);
    }
}

// Round 6
// 396.740 us; speedup vs baseline: 1.1100x; 1.1100x over previous
//
#include <hip/hip_runtime.h>
#include <math.h>
#include <stdint.h>

// Problem constants (fixed by setup_inputs)
#define NN   20000   // nodes
#define DEG  32      // neighbors per node
#define DIN  70      // 2*3 + 64 concat features
#define KP   96      // MFMA K (padded, permuted layout: [x(3) pad(5) f(64) y(3) pad(21)])
#define DH   256     // hidden
#define DC   64      // channels
#define NT   512     // threads per block (8 waves)
#define ET   128     // edges per block
#define NPB  4       // nodes per block

typedef _Float16 f16;
typedef _Float16 f16x4 __attribute__((ext_vector_type(4)));
typedef _Float16 f16x8 __attribute__((ext_vector_type(8)));
typedef float    f32x4 __attribute__((ext_vector_type(4)));

// s_agg pitch (f16); s_h uses swizzled pitch-256 addressing via h_at()
#define AGG_P 104
#define YF_P  72      // packed gather row: f(64) y(3) pad(5) -> 144 B

// f16 workspace layout (element offsets)
#define W1T_OFF 0
#define W2T_OFF (256*KP)
#define W3T_OFF (256*KP + 256*DH)
#define YF_OFF  (256*KP + 256*DH + DC*DH)
// total = 106496 + 20000*72 = 1546496 f16 = ~3.1 MB

__device__ __forceinline__ float gelu_fast(float v) {
    // exact (non-tanh) gelu via A&S 7.1.26 erf, |erf err| < 1.5e-7, branch-free
    float u  = v * 0.70710678118654752f;
    float a  = fabsf(u);
    float t  = __builtin_amdgcn_rcpf(fmaf(0.3275911f, a, 1.0f));
    float p  = fmaf(1.061405429f, t, -1.453152027f);
    p = fmaf(p, t, 1.421413741f);
    p = fmaf(p, t, -0.284496736f);
    p = fmaf(p, t, 0.254829592f);
    p = p * t;
    float e  = __expf(-u * u);
    float er = fmaf(-p, e, 1.0f);          // erf(|u|)
    er = copysignf(er, u);
    return 0.5f * v * (1.0f + er);
}

// swizzled s_h addressing: row pitch 512 B, byte_in_row ^= (row&7)<<4
// (spreads the 16 l15-rows of a wave's b128/b64 accesses across all 32 banks;
//  XOR touches byte-bits 4..6 so 8B/16B alignment is preserved)
__device__ __forceinline__ f16* h_at(f16* base, int row, int col) {
    uint32_t off = (uint32_t)(row << 9) + ((uint32_t)(col << 1) ^ (uint32_t)((row & 7) << 4));
    return (f16*)((char*)base + off);
}

// ---- pre-kernel: fp32 weights -> transposed (and for W1, column-permuted) f16 ----
// agg col k -> original feature: k<3 -> x (row 3+k); 8<=k<72 -> f (row 6+k-8);
// 72<=k<75 -> y (row k-72); else zero.
__global__ void prep_weights(const float* __restrict__ W1,
                             const float* __restrict__ W2,
                             const float* __restrict__ W3,
                             f16* __restrict__ ws)
{
    int t = blockIdx.x * blockDim.x + threadIdx.x;
    if (t < W2T_OFF) {                       // w1t: [256][96] permuted
        int n = t / KP, k = t - n * KP;
        float v;
        if (k < 3)              v = W1[(3 + k) * DH + n];        // x
        else if (k < 8)         v = 0.0f;
        else if (k < 72)        v = W1[(6 + (k - 8)) * DH + n];  // f
        else if (k < 75)        v = W1[(k - 72) * DH + n];       // y
        else                    v = 0.0f;
        ws[t] = (f16)v;
    } else if (t < W3T_OFF) {                // w2t: [256][256]
        int u = t - W2T_OFF;
        int n = u >> 8, k = u & 255;
        ws[t] = (f16)W2[k * DH + n];
    } else if (t < W3T_OFF + DC * DH) {      // w3t: [64][256]
        int u = t - W3T_OFF;
        int n = u >> 8, k = u & 255;
        ws[t] = (f16)W3[k * DC + n];
    }
}

// ---- pre-kernel: packed f16 gather table yf[n] = [f(64), y(3), pad(5)] ----
__global__ void prep_yf(const float* __restrict__ y,
                        const float* __restrict__ f_y,
                        f16* __restrict__ yf)
{
    int idx = blockIdx.x * blockDim.x + threadIdx.x;   // element index
    if (idx >= NN * YF_P) return;
    int n = idx / YF_P, c = idx - n * YF_P;
    float v;
    if (c < DC)          v = f_y[n * DC + c];
    else if (c < DC + 3) v = y[n * 3 + (c - DC)];
    else                 v = 0.0f;
    yf[idx] = (f16)v;
}

// ---- main fused kernel ----
__global__ __launch_bounds__(NT, 4)
void it_mfma_kernel(const float* __restrict__ x,
                    const float* __restrict__ wq,
                    const int*   __restrict__ nbr,
                    const float* __restrict__ b1,
                    const float* __restrict__ b2,
                    const float* __restrict__ b3,
                    const f16*  __restrict__ ws,
                    float* __restrict__ out)
{
    const int blk  = blockIdx.x;
    const int t    = threadIdx.x;
    const int lane = t & 63;
    const int w    = t >> 6;        // wave 0..7
    const int l15  = lane & 15;
    const int lk   = lane >> 4;     // 0..3

    const f16* w1t = ws + W1T_OFF;
    const f16* w2t = ws + W2T_OFF;
    const f16* w3t = ws + W3T_OFF;
    const f16* yf  = ws + YF_OFF;

    // union: agg tile (26.6 KB) aliases swizzled h tile (64 KB); agg dead after stage 1
    __shared__ __align__(16) unsigned char s_u[ET * DH * 2];    // 65536 B
    f16 (*s_agg)[AGG_P] = (f16(*)[AGG_P])s_u;
    f16* s_h0 = (f16*)s_u;
    __shared__ int   s_nbr[ET];
    __shared__ float s_wq[ET];
    __shared__ float s_red[8][DC];

    // ---- phase A: neighbor ids + quadrature weights ----
    if (t < ET) {
        int n = nbr[blk * ET + t];
        s_nbr[t] = n;
        s_wq[t]  = wq[n];
    }
    __syncthreads();

    // ---- phase B: build agg rows as 12 f16x8 chunks:
    //      chunk 0 = [x(3) 0(5)], chunks 1..9 = yfr[0..71], chunks 10,11 = 0
    {
        const int e    = t >> 2;        // 0..127
        const int part = t & 3;
        const f16* yfr = yf + (size_t)s_nbr[e] * YF_P;
        f16* aggr = &s_agg[e][0];
        #pragma unroll
        for (int j = 0; j < 3; ++j) {
            int ch = part * 3 + j;      // 0..11, each chunk exactly once
            if (ch == 0) {
                int node = blk * NPB + (e >> 5);
                f16x8 v = {};
                v[0] = (f16)x[node*3 + 0];
                v[1] = (f16)x[node*3 + 1];
                v[2] = (f16)x[node*3 + 2];
                *(f16x8*)&aggr[0] = v;
            } else if (ch <= 9) {
                *(f16x8*)&aggr[8*ch] = *(const f16x8*)&yfr[8*(ch-1)];
            } else {
                *(f16x8*)&aggr[8*ch] = (f16x8){};
            }
        }
    }
    __syncthreads();

    // wave partition for GEMM1/2: 2 M-groups x 4 N-groups
    const int m_base = (w >> 2) * 64;
    const int n_base = (w & 3) * 64;

    f32x4 acc[4][4];

    // ---- stage 1: h1 = gelu(agg @ W1p + b1), K = 96 (swapped mfma -> D=h^T) ----
    #pragma unroll
    for (int nj = 0; nj < 4; ++nj) {
        float4 bv = *(const float4*)&b1[n_base + nj*16 + lk*4];
        #pragma unroll
        for (int mi = 0; mi < 4; ++mi) acc[mi][nj] = (f32x4){bv.x, bv.y, bv.z, bv.w};
    }
    #pragma unroll
    for (int ks = 0; ks < KP/32; ++ks) {
        const int k0 = ks*32 + lk*8;
        f16x8 a[4], b[4];
        #pragma unroll
        for (int mi = 0; mi < 4; ++mi)
            a[mi] = *(const f16x8*)&s_agg[m_base + mi*16 + l15][k0];
        #pragma unroll
        for (int nj = 0; nj < 4; ++nj)
            b[nj] = *(const f16x8*)&w1t[(n_base + nj*16 + l15) * KP + k0];
        #pragma unroll
        for (int mi = 0; mi < 4; ++mi)
            #pragma unroll
            for (int nj = 0; nj < 4; ++nj)
                acc[mi][nj] = __builtin_amdgcn_mfma_f32_16x16x32_f16(b[nj], a[mi], acc[mi][nj], 0, 0, 0);
    }
    __syncthreads();   // ALL waves done reading s_agg before h1 overwrites the union
    #pragma unroll
    for (int mi = 0; mi < 4; ++mi)
        #pragma unroll
        for (int nj = 0; nj < 4; ++nj) {
            int e  = m_base + mi*16 + l15;
            int n0 = n_base + nj*16 + lk*4;
            f16x4 hv;
            #pragma unroll
            for (int r = 0; r < 4; ++r) hv[r] = (f16)gelu_fast(acc[mi][nj][r]);
            *(f16x4*)h_at(s_h0, e, n0) = hv;
        }
    __syncthreads();

    // ---- stage 2: h2 = gelu(h1 @ W2 + b2), K = 256 (swapped) ----
    #pragma unroll
    for (int nj = 0; nj < 4; ++nj) {
        float4 bv = *(const float4*)&b2[n_base + nj*16 + lk*4];
        #pragma unroll
        for (int mi = 0; mi < 4; ++mi) acc[mi][nj] = (f32x4){bv.x, bv.y, bv.z, bv.w};
    }
    #pragma unroll 2
    for (int ks = 0; ks < DH/32; ++ks) {
        const int k0 = ks*32 + lk*8;
        f16x8 a[4], b[4];
        #pragma unroll
        for (int mi = 0; mi < 4; ++mi)
            a[mi] = *(const f16x8*)h_at(s_h0, m_base + mi*16 + l15, k0);
        #pragma unroll
        for (int nj = 0; nj < 4; ++nj)
            b[nj] = *(const f16x8*)&w2t[(n_base + nj*16 + l15) * DH + k0];
        #pragma unroll
        for (int mi = 0; mi < 4; ++mi)
            #pragma unroll
            for (int nj = 0; nj < 4; ++nj)
                acc[mi][nj] = __builtin_amdgcn_mfma_f32_16x16x32_f16(b[nj], a[mi], acc[mi][nj], 0, 0, 0);
    }
    __syncthreads();   // all waves done reading h1 before overwrite
    #pragma unroll
    for (int mi = 0; mi < 4; ++mi)
        #pragma unroll
        for (int nj = 0; nj < 4; ++nj) {
            int e  = m_base + mi*16 + l15;
            int n0 = n_base + nj*16 + lk*4;
            f16x4 hv;
            #pragma unroll
            for (int r = 0; r < 4; ++r) hv[r] = (f16)gelu_fast(acc[mi][nj][r]);
            *(f16x4*)h_at(s_h0, e, n0) = hv;
        }
    __syncthreads();

    // ---- stage 3: k3 = h2 @ W3 + b3; msg = wq*k3*f; segment reduce ----
    // unswapped: lane col = channel (l15 in nj tile), rows = edges (lk*4+r)
    {
        float fv[4][4]; float wqe[4];
        #pragma unroll
        for (int r = 0; r < 4; ++r) {
            int e = w*16 + lk*4 + r;
            const f16* yfr = yf + (size_t)s_nbr[e] * YF_P;
            wqe[r] = s_wq[e];
            #pragma unroll
            for (int nj = 0; nj < 4; ++nj)
                fv[r][nj] = (float)yfr[nj*16 + l15];
        }
        f32x4 acc3[4];
        #pragma unroll
        for (int nj = 0; nj < 4; ++nj) {
            float bv = b3[nj*16 + l15];
            acc3[nj] = (f32x4){bv, bv, bv, bv};
        }
        #pragma unroll 2
        for (int ks = 0; ks < DH/32; ++ks) {
            const int k0 = ks*32 + lk*8;
            f16x8 a = *(const f16x8*)h_at(s_h0, w*16 + l15, k0);
            #pragma unroll
            for (int nj = 0; nj < 4; ++nj) {
                f16x8 b = *(const f16x8*)&w3t[(nj*16 + l15) * DH + k0];
                acc3[nj] = __builtin_amdgcn_mfma_f32_16x16x32_f16(a, b, acc3[nj], 0, 0, 0);
            }
        }
        float part[4];
        #pragma unroll
        for (int nj = 0; nj < 4; ++nj) {
            float s = 0.f;
            #pragma unroll
            for (int r = 0; r < 4; ++r)
                s = fmaf(wqe[r] * acc3[nj][r], fv[r][nj], s);
            part[nj] = s;
        }
        #pragma unroll
        for (int nj = 0; nj < 4; ++nj) {
            part[nj] += __shfl_xor(part[nj], 16, 64);
            part[nj] += __shfl_xor(part[nj], 32, 64);
        }
        if (lane < 16) {
            #pragma unroll
            for (int nj = 0; nj < 4; ++nj) s_red[w][nj*16 + l15] = part[nj];
        }
    }
    __syncthreads();

    if (t < NPB * DC) {
        int node = t >> 6, c = t & 63;
        out[(blk * NPB + node) * DC + c] = s_red[2*node][c] + s_red[2*node + 1][c];
    }
}

extern "C" void kernel_launch(void* const* d_in, const int* in_sizes, int n_in,
                              void* d_out, int out_size, void* d_ws, size_t ws_size,
                              hipStream_t stream) {
    const float* y   = (const float*)d_in[0];
    const float* x   = (const float*)d_in[1];
    const float* f_y = (const float*)d_in[2];
    const float* wq  = (const float*)d_in[3];
    const int*   nbr = (const int*)d_in[4];
    // d_in[5] = neighbors_row_splits (uniform arange*DEG, unused)
    const float* W1  = (const float*)d_in[6];
    const float* b1  = (const float*)d_in[7];
    const float* W2  = (const float*)d_in[8];
    const float* b2  = (const float*)d_in[9];
    const float* W3  = (const float*)d_in[10];
    const float* b3  = (const float*)d_in[11];
    float* out = (float*)d_out;
    f16*   ws  = (f16*)d_ws;

    hipLaunchKernelGGL(prep_weights, dim3((W3T_OFF + DC*DH + 255) / 256), dim3(256), 0, stream,
                       W1, W2, W3, ws);
    hipLaunchKernelGGL(prep_yf, dim3((NN * YF_P + 255) / 256), dim3(256), 0, stream,
                       y, f_y, ws + YF_OFF);
    hipLaunchKernelGGL(it_mfma_kernel, dim3(NN / NPB), dim3(NT), 0, stream,
                       x, wq, nbr, b1, b2, b3, ws, out);
}